// Round 8
// baseline (162.778 us; speedup 1.0000x reference)
//
#include <hip/hip_runtime.h>
#include <hip/hip_bf16.h>

// Problem constants (B=32, N=256, K=20, channels 3->64->128->256, fc 256->128->40)
#define B_ 32
#define N_ 256
#define K_ 20
#define C1 64
#define C2 128
#define C3 256
#define F1 128
#define F2 40
#define NEG_INF (-3.402823466e38f)

// DPP controls
#define DPP_QUAD_XOR1 0xB1   // quad_perm [1,0,3,2]
#define DPP_QUAD_XOR2 0x4E   // quad_perm [2,3,0,1]
#define DPP_HALF_MIRR 0x141  // row_half_mirror (pairs l <-> 7-l within 8)
#define DPP_ROW_MIRR  0x140  // row_mirror      (pairs l <-> 15-l within 16)

__device__ __forceinline__ unsigned wave_max_u32(unsigned v) {
    unsigned m;
    m = (unsigned)__builtin_amdgcn_update_dpp(0, (int)v, DPP_QUAD_XOR1, 0xF, 0xF, true);
    v = m > v ? m : v;
    m = (unsigned)__builtin_amdgcn_update_dpp(0, (int)v, DPP_QUAD_XOR2, 0xF, 0xF, true);
    v = m > v ? m : v;
    m = (unsigned)__builtin_amdgcn_update_dpp(0, (int)v, DPP_HALF_MIRR, 0xF, 0xF, true);
    v = m > v ? m : v;
    m = (unsigned)__builtin_amdgcn_update_dpp(0, (int)v, DPP_ROW_MIRR, 0xF, 0xF, true);
    v = m > v ? m : v;
    m = (unsigned)__builtin_amdgcn_ds_swizzle((int)v, 0x401F);  // lane ^ 16
    v = m > v ? m : v;
    m = (unsigned)__shfl_xor((int)v, 32, 64);                   // lane ^ 32
    v = m > v ? m : v;
    return v;   // bitwise-identical max in all 64 lanes
}

// ---------------------------------------------------------------------------
// NODE 1: three independent block families (no cross-family dependency):
//   blocks [0,512):     per-point MLP 3->64->128->256. Lane owns oc-chunk with
//                       per-lane raw weight-row loads (L2-served, no prep);
//                       activations LDS-broadcast (wave-uniform addresses).
//   blocks [512,2560):  per-point top-20, one wave per point. Candidates read
//                       straight from global (xb = 3 KB, L1-resident); u32
//                       monotone keys; max-reduce = 4 DPP stages + 2 LDS ops;
//                       exact lowest-index tie-break via ballot + scalar ffs.
//   blocks [2560,2576): fc1 weight transpose fc1T[n][j] = fc1w[j][n].
// ---------------------------------------------------------------------------
__global__ __launch_bounds__(256) void k_front(const float* __restrict__ x,
    const float* __restrict__ w1, const float* __restrict__ s1, const float* __restrict__ b1,
    const float* __restrict__ w2, const float* __restrict__ s2, const float* __restrict__ b2,
    const float* __restrict__ w3, const float* __restrict__ s3, const float* __restrict__ b3,
    const float* __restrict__ fc1w,
    int* __restrict__ idx, float* __restrict__ P, float* __restrict__ fc1T) {

    __shared__ float smem[3136];        // mlp only: xs 64 | y1 1024 | y2 2048
    const int blk  = blockIdx.x;
    const int t    = threadIdx.x;
    const int lane = t & 63;
    const int wv   = t >> 6;

    if (blk < 512) {
        // ================== per-point MLP, 16 points/block ==================
        float* xs = smem;               // 48 used
        float* y1 = smem + 64;          // [c1][p] 64x16
        float* y2 = smem + 1088;        // [c2][p] 128x16
        const int pbase = blk * 16;
        const int p0 = wv * 4;          // wave's 4-point quad

        if (t < 48) xs[t] = x[(size_t)pbase * 3 + t];
        __syncthreads();

        // ---- layer 1: 64 x 3; thread = (oc, pt-quad) ----
        {
            const int oc = lane;
            const float wa = w1[oc * 3 + 0], wb = w1[oc * 3 + 1], wc = w1[oc * 3 + 2];
            const float sc = s1[oc], sh = b1[oc];
            float4 v;
            #pragma unroll
            for (int p = 0; p < 4; ++p) {
                const int pp = p0 + p;
                float vv = wa * xs[pp * 3 + 0] + wb * xs[pp * 3 + 1] + wc * xs[pp * 3 + 2];
                (&v.x)[p] = fmaxf(vv * sc + sh, 0.0f);
            }
            *(float4*)&y1[oc * 16 + p0] = v;
        }
        __syncthreads();

        // ---- layer 2: 128oc x 64k; lane owns oc {2l,2l+1}, wave owns pt-quad ----
        {
            float acc[2][4] = {};
            const float4* wr0 = (const float4*)(w2 + (size_t)(lane * 2) * C1);
            const float4* wr1 = (const float4*)(w2 + (size_t)(lane * 2 + 1) * C1);
            for (int k = 0; k < C1; k += 4) {
                float4 a[4];
                #pragma unroll
                for (int kk = 0; kk < 4; ++kk)
                    a[kk] = *(const float4*)&y1[(k + kk) * 16 + p0];    // broadcast
                const float4 wA = wr0[k >> 2];                          // per-lane row
                const float4 wB = wr1[k >> 2];
                #pragma unroll
                for (int kk = 0; kk < 4; ++kk) {
                    #pragma unroll
                    for (int p = 0; p < 4; ++p) {
                        acc[0][p] += (&wA.x)[kk] * (&a[kk].x)[p];
                        acc[1][p] += (&wB.x)[kk] * (&a[kk].x)[p];
                    }
                }
            }
            const float2 sc = *(const float2*)&s2[lane * 2];
            const float2 sh = *(const float2*)&b2[lane * 2];
            float4 v0, v1;
            #pragma unroll
            for (int p = 0; p < 4; ++p) {
                (&v0.x)[p] = fmaxf(acc[0][p] * sc.x + sh.x, 0.0f);
                (&v1.x)[p] = fmaxf(acc[1][p] * sc.y + sh.y, 0.0f);
            }
            *(float4*)&y2[(lane * 2) * 16 + p0]     = v0;
            *(float4*)&y2[(lane * 2 + 1) * 16 + p0] = v1;
        }
        __syncthreads();

        // ---- layer 3: 256oc x 128k; lane owns oc [4l,4l+4), wave owns pt-quad ----
        {
            float acc[4][4] = {};
            for (int k = 0; k < C2; k += 4) {
                float4 a[4];
                #pragma unroll
                for (int kk = 0; kk < 4; ++kk)
                    a[kk] = *(const float4*)&y2[(k + kk) * 16 + p0];    // broadcast
                float4 w[4];
                #pragma unroll
                for (int o = 0; o < 4; ++o)
                    w[o] = *(const float4*)(w3 + (size_t)(lane * 4 + o) * C2 + k);
                #pragma unroll
                for (int o = 0; o < 4; ++o) {
                    #pragma unroll
                    for (int kk = 0; kk < 4; ++kk) {
                        const float wvv = (&w[o].x)[kk];
                        #pragma unroll
                        for (int p = 0; p < 4; ++p)
                            acc[o][p] += wvv * (&a[kk].x)[p];
                    }
                }
            }
            const float4 sc = *(const float4*)&s3[lane * 4];
            const float4 sh = *(const float4*)&b3[lane * 4];
            #pragma unroll
            for (int p = 0; p < 4; ++p) {
                float4 v;
                #pragma unroll
                for (int o = 0; o < 4; ++o)
                    (&v.x)[o] = fmaxf(acc[o][p] * (&sc.x)[o] + (&sh.x)[o], 0.0f);
                *(float4*)&P[(size_t)(pbase + p0 + p) * C3 + lane * 4] = v;  // coalesced
            }
        }

    } else if (blk < 2560) {
        // ================== top-20, one wave per point, LDS-free ==================
        const int tb = blk - 512;
        const int b  = tb >> 6;
        const int n  = ((tb & 63) << 2) | wv;
        const int bn = (b << 8) | n;
        const float* xb = x + (size_t)b * N_ * 3;

        const float nx = xb[n * 3 + 0], ny = xb[n * 3 + 1], nz = xb[n * 3 + 2];
        const float xxn = nx * nx + ny * ny + nz * nz;

        unsigned k0, k1, k2, k3;
        {
            unsigned kk[4];
            #pragma unroll
            for (int i = 0; i < 4; ++i) {
                const int m = lane + (i << 6);
                const float cx = xb[m * 3 + 0], cy = xb[m * 3 + 1], cz = xb[m * 3 + 2];
                const float xxm = cx * cx + cy * cy + cz * cz;
                const float v = 2.0f * (nx * cx + ny * cy + nz * cz) - xxn - xxm;
                const unsigned u = __float_as_uint(v);
                kk[i] = (u & 0x80000000u) ? ~u : (u | 0x80000000u);   // monotone
            }
            k0 = kk[0]; k1 = kk[1]; k2 = kk[2]; k3 = kk[3];
        }

        int mine = 0;
        #pragma unroll 1
        for (int it = 0; it < K_; ++it) {
            unsigned ra = k0 > k1 ? k0 : k1;
            unsigned rb = k2 > k3 ? k2 : k3;
            const unsigned M = wave_max_u32(ra > rb ? ra : rb);
            // lowest candidate index holding M (exact lax.top_k tie-break)
            const unsigned long long b0 = __ballot(k0 == M);
            const unsigned long long b1 = __ballot(k1 == M);
            const unsigned long long b2m = __ballot(k2 == M);
            const unsigned long long b3m = __ballot(k3 == M);
            int ri;
            if      (b0)  ri = __ffsll((long long)b0) - 1;
            else if (b1)  ri = 64  + __ffsll((long long)b1) - 1;
            else if (b2m) ri = 128 + __ffsll((long long)b2m) - 1;
            else          ri = 192 + __ffsll((long long)b3m) - 1;
            if (lane == it) mine = ri;
            if (lane == (ri & 63)) {
                const int slot = ri >> 6;
                if      (slot == 0) k0 = 0u;
                else if (slot == 1) k1 = 0u;
                else if (slot == 2) k2 = 0u;
                else                k3 = 0u;
            }
        }
        if (lane < K_) idx[(size_t)bn * K_ + lane] = mine;

    } else {
        // ================== fc1 weight transpose ==================
        const int g = (blk - 2560) * 256 + t;   // 0..4095
        #pragma unroll
        for (int i = 0; i < 8; ++i) {           // 32768 elems
            const int e = g + i * 4096;
            const int j = e >> 8, n = e & 255;
            fc1T[n * F1 + j] = fc1w[e];
        }
    }
}

// ---------------------------------------------------------------------------
// NODE 2: FUSED gather-max + fc1(relu) + fc2 (unchanged from R5/R7).
// 512 blocks = (b, 16-ch tile) x 256 threads.
// ---------------------------------------------------------------------------
__global__ __launch_bounds__(256) void k_gfc(const float* __restrict__ P,
                                             const int* __restrict__ idx,
                                             const float* __restrict__ fc1T,
                                             const float* __restrict__ fc1b,
                                             const float* __restrict__ fc2w,
                                             const float* __restrict__ fc2b,
                                             float* __restrict__ out) {
    const int b    = blockIdx.x >> 4;
    const int ch0  = (blockIdx.x & 15) * 16;
    const int t    = threadIdx.x;
    const int lane = t & 63;

    __shared__ float Ht[N_ * 16];       // [n][ci], 16 KB
    __shared__ float gl[16 * 132];      // [ci][j], padded stride 132
    __shared__ float w2l[F2 * 129];     // [m][j], padded (129 = 1 mod 32)

    for (int e = t; e < F2 * F1; e += 256)
        w2l[(e >> 7) * 129 + (e & 127)] = fc2w[e];

    // ---- stage A: gather-max into Ht ----
    {
        const int q  = t & 3;           // ch-quad
        const int nl = t >> 2;          // n within quarter-pass
        const float* Pq = P + (size_t)b * N_ * C3 + ch0 + q * 4;
        #pragma unroll
        for (int r = 0; r < 4; ++r) {
            const int n = r * 64 + nl;
            const int* ib = idx + ((size_t)((b << 8) | n)) * K_;
            float4 m = make_float4(NEG_INF, NEG_INF, NEG_INF, NEG_INF);
            #pragma unroll
            for (int j = 0; j < K_; ++j) {
                const int id = ib[j];
                const float4 p = *(const float4*)(Pq + (size_t)id * C3);
                m.x = fmaxf(m.x, p.x);
                m.y = fmaxf(m.y, p.y);
                m.z = fmaxf(m.z, p.z);
                m.w = fmaxf(m.w, p.w);
            }
            *(float4*)&Ht[n * 16 + q * 4] = m;
        }
    }
    __syncthreads();

    // ---- stage B: fc1 + relu -> gl[ci][j] ----
    {
        const int c0 = (t >> 6) * 4;    // wave's ch-quad
        float acc[2][4] = {};
        #pragma unroll 4
        for (int n = 0; n < N_; ++n) {
            const float2 w = *(const float2*)&fc1T[n * F1 + lane * 2];  // coalesced
            const float4 a = *(const float4*)&Ht[n * 16 + c0];          // broadcast
            #pragma unroll
            for (int c = 0; c < 4; ++c) {
                acc[0][c] += w.x * (&a.x)[c];
                acc[1][c] += w.y * (&a.x)[c];
            }
        }
        const float bb0 = fc1b[lane * 2], bb1 = fc1b[lane * 2 + 1];
        #pragma unroll
        for (int c = 0; c < 4; ++c) {
            float2 v;
            v.x = fmaxf(acc[0][c] + bb0, 0.0f);
            v.y = fmaxf(acc[1][c] + bb1, 0.0f);
            *(float2*)&gl[(c0 + c) * 132 + lane * 2] = v;
        }
    }
    __syncthreads();

    // ---- stage C: fc2 -> out ----
    for (int o = t; o < 16 * F2; o += 256) {
        const int ci = o / F2;
        const int m  = o % F2;
        float acc = fc2b[m];
        const float* wr = w2l + m * 129;
        const float* gr = gl + ci * 132;
        #pragma unroll 4
        for (int j = 0; j < F1; ++j)
            acc += wr[j] * gr[j];
        out[((size_t)(b * C3 + ch0 + ci)) * F2 + m] = acc;
    }
}

// ---------------------------------------------------------------------------
extern "C" void kernel_launch(void* const* d_in, const int* in_sizes, int n_in,
                              void* d_out, int out_size, void* d_ws, size_t ws_size,
                              hipStream_t stream) {
    const float* x    = (const float*)d_in[0];
    const float* w1   = (const float*)d_in[1];
    const float* s1   = (const float*)d_in[2];
    const float* t1   = (const float*)d_in[3];
    const float* w2   = (const float*)d_in[4];
    const float* s2   = (const float*)d_in[5];
    const float* t2   = (const float*)d_in[6];
    const float* w3   = (const float*)d_in[7];
    const float* s3   = (const float*)d_in[8];
    const float* t3   = (const float*)d_in[9];
    const float* fc1w = (const float*)d_in[10];
    const float* fc1b = (const float*)d_in[11];
    const float* fc2w = (const float*)d_in[12];
    const float* fc2b = (const float*)d_in[13];
    float* out = (float*)d_out;

    // Workspace layout (all fully overwritten every call):
    char* ws = (char*)d_ws;
    int*   idx  = (int*)ws;                                  // 655,360 B
    float* P    = (float*)(ws + (size_t)B_ * N_ * K_ * 4);   // 8 MB
    float* fc1T = P + (size_t)B_ * N_ * C3;                  // 131,072 B

    k_front<<<2576, 256, 0, stream>>>(x, w1, s1, t1, w2, s2, t2, w3, s3, t3,
                                      fc1w, idx, P, fc1T);
    k_gfc<<<B_ * 16, 256, 0, stream>>>(P, idx, fc1T, fc1b, fc2w, fc2b, out);
}

// Round 9
// 133.903 us; speedup vs baseline: 1.2156x; 1.2156x over previous
//
#include <hip/hip_runtime.h>
#include <hip/hip_bf16.h>

// Problem constants (B=32, N=256, K=20, channels 3->64->128->256, fc 256->128->40)
#define B_ 32
#define N_ 256
#define K_ 20
#define C1 64
#define C2 128
#define C3 256
#define F1 128
#define F2 40
#define NEG_INF (-3.402823466e38f)

// DPP controls
#define DPP_QUAD_XOR1 0xB1   // quad_perm [1,0,3,2]
#define DPP_QUAD_XOR2 0x4E   // quad_perm [2,3,0,1]
#define DPP_HALF_MIRR 0x141  // row_half_mirror
#define DPP_ROW_MIRR  0x140  // row_mirror

__device__ __forceinline__ unsigned wave_max_u32(unsigned v) {
    unsigned m;
    m = (unsigned)__builtin_amdgcn_update_dpp(0, (int)v, DPP_QUAD_XOR1, 0xF, 0xF, true);
    v = m > v ? m : v;
    m = (unsigned)__builtin_amdgcn_update_dpp(0, (int)v, DPP_QUAD_XOR2, 0xF, 0xF, true);
    v = m > v ? m : v;
    m = (unsigned)__builtin_amdgcn_update_dpp(0, (int)v, DPP_HALF_MIRR, 0xF, 0xF, true);
    v = m > v ? m : v;
    m = (unsigned)__builtin_amdgcn_update_dpp(0, (int)v, DPP_ROW_MIRR, 0xF, 0xF, true);
    v = m > v ? m : v;
    m = (unsigned)__builtin_amdgcn_ds_swizzle((int)v, 0x401F);  // lane ^ 16
    v = m > v ? m : v;
    m = (unsigned)__shfl_xor((int)v, 32, 64);                   // lane ^ 32
    v = m > v ? m : v;
    return v;   // bitwise-identical max in all 64 lanes
}

// ---------------------------------------------------------------------------
// NODE 1: three independent block families:
//   blocks [0,512):     per-point MLP, 16 pts/block. Thread = (oc-group,
//                       pt-quad) with the 4 pt-quad lanes ADJACENT -> weight
//                       addresses duplicate within a 4-lane group and merge in
//                       the coalescer (1x row coverage per block), while each
//                       activation ds_read_b128 feeds 4x FMAs.
//   blocks [512,2560):  per-point top-20, one wave per point, LDS-free:
//                       u32 monotone keys, DPP+swizzle max-reduce, exact
//                       lowest-index tie-break via ballot+ffs.
//   blocks [2560,2576): fc1 weight transpose fc1T[n][j] = fc1w[j][n].
// ---------------------------------------------------------------------------
__global__ __launch_bounds__(256) void k_front(const float* __restrict__ x,
    const float* __restrict__ w1, const float* __restrict__ s1, const float* __restrict__ b1,
    const float* __restrict__ w2, const float* __restrict__ s2, const float* __restrict__ b2,
    const float* __restrict__ w3, const float* __restrict__ s3, const float* __restrict__ b3,
    const float* __restrict__ fc1w,
    int* __restrict__ idx, float* __restrict__ P, float* __restrict__ fc1T) {

    __shared__ float smem[3136];        // mlp only: xs 64 | y1 1024 | y2 2048
    const int blk  = blockIdx.x;
    const int t    = threadIdx.x;
    const int lane = t & 63;
    const int wv   = t >> 6;

    if (blk < 512) {
        // ================== per-point MLP, 16 points/block ==================
        float* xs = smem;               // 48 used
        float* y1 = smem + 64;          // [c1][p] 64x16
        float* y2 = smem + 1088;        // [c2][p] 128x16
        const int pbase = blk * 16;
        const int og = t >> 2;          // oc-group 0..63 (4 adjacent lanes share)
        const int p0 = (t & 3) * 4;     // pt-quad

        if (t < 48) xs[t] = x[(size_t)pbase * 3 + t];
        __syncthreads();

        // ---- layer 1: 64 x 3; thread = (oc=lane, pt-quad=wv) ----
        {
            const int oc = lane;
            const float wa = w1[oc * 3 + 0], wb = w1[oc * 3 + 1], wc = w1[oc * 3 + 2];
            const float sc = s1[oc], sh = b1[oc];
            const int q0 = wv * 4;
            float4 v;
            #pragma unroll
            for (int p = 0; p < 4; ++p) {
                const int pp = q0 + p;
                float vv = wa * xs[pp * 3 + 0] + wb * xs[pp * 3 + 1] + wc * xs[pp * 3 + 2];
                (&v.x)[p] = fmaxf(vv * sc + sh, 0.0f);
            }
            *(float4*)&y1[oc * 16 + q0] = v;
        }
        __syncthreads();

        // ---- layer 2: 128oc x 64k; thread = (2-oc group og, pt-quad) ----
        {
            const int oc0 = og * 2;
            float acc[2][4] = {};
            for (int k = 0; k < C1; k += 4) {
                float4 a[4];
                #pragma unroll
                for (int kk = 0; kk < 4; ++kk)
                    a[kk] = *(const float4*)&y1[(k + kk) * 16 + p0];
                const float4 wA = *(const float4*)(w2 + (size_t)oc0 * C1 + k);       // 4-lane dup
                const float4 wB = *(const float4*)(w2 + (size_t)(oc0 + 1) * C1 + k); // merges
                #pragma unroll
                for (int kk = 0; kk < 4; ++kk) {
                    #pragma unroll
                    for (int p = 0; p < 4; ++p) {
                        acc[0][p] += (&wA.x)[kk] * (&a[kk].x)[p];
                        acc[1][p] += (&wB.x)[kk] * (&a[kk].x)[p];
                    }
                }
            }
            const float sc0 = s2[oc0], sh0 = b2[oc0];
            const float sc1 = s2[oc0 + 1], sh1 = b2[oc0 + 1];
            float4 v0, v1;
            #pragma unroll
            for (int p = 0; p < 4; ++p) {
                (&v0.x)[p] = fmaxf(acc[0][p] * sc0 + sh0, 0.0f);
                (&v1.x)[p] = fmaxf(acc[1][p] * sc1 + sh1, 0.0f);
            }
            *(float4*)&y2[oc0 * 16 + p0]       = v0;
            *(float4*)&y2[(oc0 + 1) * 16 + p0] = v1;
        }
        __syncthreads();

        // ---- layer 3: 256oc x 128k; thread = (4-oc group og, pt-quad) ----
        {
            const int oc0 = og * 4;
            float acc[4][4] = {};
            for (int k = 0; k < C2; k += 4) {
                float4 a[4];
                #pragma unroll
                for (int kk = 0; kk < 4; ++kk)
                    a[kk] = *(const float4*)&y2[(k + kk) * 16 + p0];
                float4 w[4];
                #pragma unroll
                for (int o = 0; o < 4; ++o)
                    w[o] = *(const float4*)(w3 + (size_t)(oc0 + o) * C2 + k);        // 4-lane dup
                #pragma unroll
                for (int o = 0; o < 4; ++o) {
                    #pragma unroll
                    for (int kk = 0; kk < 4; ++kk) {
                        const float wvv = (&w[o].x)[kk];
                        #pragma unroll
                        for (int p = 0; p < 4; ++p)
                            acc[o][p] += wvv * (&a[kk].x)[p];
                    }
                }
            }
            const float4 sc = *(const float4*)&s3[oc0];
            const float4 sh = *(const float4*)&b3[oc0];
            #pragma unroll
            for (int p = 0; p < 4; ++p) {
                float4 v;
                #pragma unroll
                for (int o = 0; o < 4; ++o)
                    (&v.x)[o] = fmaxf(acc[o][p] * (&sc.x)[o] + (&sh.x)[o], 0.0f);
                *(float4*)&P[(size_t)(pbase + p0 + p) * C3 + oc0] = v;
            }
        }

    } else if (blk < 2560) {
        // ================== top-20, one wave per point, LDS-free ==================
        const int tb = blk - 512;
        const int b  = tb >> 6;
        const int n  = ((tb & 63) << 2) | wv;
        const int bn = (b << 8) | n;
        const float* xb = x + (size_t)b * N_ * 3;

        const float nx = xb[n * 3 + 0], ny = xb[n * 3 + 1], nz = xb[n * 3 + 2];
        const float xxn = nx * nx + ny * ny + nz * nz;

        unsigned k0, k1, k2, k3;
        {
            unsigned kk[4];
            #pragma unroll
            for (int i = 0; i < 4; ++i) {
                const int m = lane + (i << 6);
                const float cx = xb[m * 3 + 0], cy = xb[m * 3 + 1], cz = xb[m * 3 + 2];
                const float xxm = cx * cx + cy * cy + cz * cz;
                const float v = 2.0f * (nx * cx + ny * cy + nz * cz) - xxn - xxm;
                const unsigned u = __float_as_uint(v);
                kk[i] = (u & 0x80000000u) ? ~u : (u | 0x80000000u);   // monotone
            }
            k0 = kk[0]; k1 = kk[1]; k2 = kk[2]; k3 = kk[3];
        }

        int mine = 0;
        #pragma unroll 1
        for (int it = 0; it < K_; ++it) {
            unsigned ra = k0 > k1 ? k0 : k1;
            unsigned rb = k2 > k3 ? k2 : k3;
            const unsigned M = wave_max_u32(ra > rb ? ra : rb);
            const unsigned long long b0 = __ballot(k0 == M);
            const unsigned long long b1 = __ballot(k1 == M);
            const unsigned long long b2m = __ballot(k2 == M);
            const unsigned long long b3m = __ballot(k3 == M);
            int ri;
            if      (b0)  ri = __ffsll((long long)b0) - 1;
            else if (b1)  ri = 64  + __ffsll((long long)b1) - 1;
            else if (b2m) ri = 128 + __ffsll((long long)b2m) - 1;
            else          ri = 192 + __ffsll((long long)b3m) - 1;
            if (lane == it) mine = ri;
            if (lane == (ri & 63)) {
                const int slot = ri >> 6;
                if      (slot == 0) k0 = 0u;
                else if (slot == 1) k1 = 0u;
                else if (slot == 2) k2 = 0u;
                else                k3 = 0u;
            }
        }
        if (lane < K_) idx[(size_t)bn * K_ + lane] = mine;

    } else {
        // ================== fc1 weight transpose ==================
        const int g = (blk - 2560) * 256 + t;   // 0..4095
        #pragma unroll
        for (int i = 0; i < 8; ++i) {           // 32768 elems
            const int e = g + i * 4096;
            const int j = e >> 8, n = e & 255;
            fc1T[n * F1 + j] = fc1w[e];
        }
    }
}

// ---------------------------------------------------------------------------
// NODE 2: FUSED gather-max + fc1(relu) + fc2 (unchanged since R5).
// 512 blocks = (b, 16-ch tile) x 256 threads.
// ---------------------------------------------------------------------------
__global__ __launch_bounds__(256) void k_gfc(const float* __restrict__ P,
                                             const int* __restrict__ idx,
                                             const float* __restrict__ fc1T,
                                             const float* __restrict__ fc1b,
                                             const float* __restrict__ fc2w,
                                             const float* __restrict__ fc2b,
                                             float* __restrict__ out) {
    const int b    = blockIdx.x >> 4;
    const int ch0  = (blockIdx.x & 15) * 16;
    const int t    = threadIdx.x;
    const int lane = t & 63;

    __shared__ float Ht[N_ * 16];       // [n][ci], 16 KB
    __shared__ float gl[16 * 132];      // [ci][j], padded stride 132
    __shared__ float w2l[F2 * 129];     // [m][j], padded (129 = 1 mod 32)

    for (int e = t; e < F2 * F1; e += 256)
        w2l[(e >> 7) * 129 + (e & 127)] = fc2w[e];

    // ---- stage A: gather-max into Ht ----
    {
        const int q  = t & 3;           // ch-quad
        const int nl = t >> 2;          // n within quarter-pass
        const float* Pq = P + (size_t)b * N_ * C3 + ch0 + q * 4;
        #pragma unroll
        for (int r = 0; r < 4; ++r) {
            const int n = r * 64 + nl;
            const int* ib = idx + ((size_t)((b << 8) | n)) * K_;
            float4 m = make_float4(NEG_INF, NEG_INF, NEG_INF, NEG_INF);
            #pragma unroll
            for (int j = 0; j < K_; ++j) {
                const int id = ib[j];
                const float4 p = *(const float4*)(Pq + (size_t)id * C3);
                m.x = fmaxf(m.x, p.x);
                m.y = fmaxf(m.y, p.y);
                m.z = fmaxf(m.z, p.z);
                m.w = fmaxf(m.w, p.w);
            }
            *(float4*)&Ht[n * 16 + q * 4] = m;
        }
    }
    __syncthreads();

    // ---- stage B: fc1 + relu -> gl[ci][j] ----
    {
        const int c0 = (t >> 6) * 4;    // wave's ch-quad
        float acc[2][4] = {};
        #pragma unroll 4
        for (int n = 0; n < N_; ++n) {
            const float2 w = *(const float2*)&fc1T[n * F1 + lane * 2];  // coalesced
            const float4 a = *(const float4*)&Ht[n * 16 + c0];          // broadcast
            #pragma unroll
            for (int c = 0; c < 4; ++c) {
                acc[0][c] += w.x * (&a.x)[c];
                acc[1][c] += w.y * (&a.x)[c];
            }
        }
        const float bb0 = fc1b[lane * 2], bb1 = fc1b[lane * 2 + 1];
        #pragma unroll
        for (int c = 0; c < 4; ++c) {
            float2 v;
            v.x = fmaxf(acc[0][c] + bb0, 0.0f);
            v.y = fmaxf(acc[1][c] + bb1, 0.0f);
            *(float2*)&gl[(c0 + c) * 132 + lane * 2] = v;
        }
    }
    __syncthreads();

    // ---- stage C: fc2 -> out ----
    for (int o = t; o < 16 * F2; o += 256) {
        const int ci = o / F2;
        const int m  = o % F2;
        float acc = fc2b[m];
        const float* wr = w2l + m * 129;
        const float* gr = gl + ci * 132;
        #pragma unroll 4
        for (int j = 0; j < F1; ++j)
            acc += wr[j] * gr[j];
        out[((size_t)(b * C3 + ch0 + ci)) * F2 + m] = acc;
    }
}

// ---------------------------------------------------------------------------
extern "C" void kernel_launch(void* const* d_in, const int* in_sizes, int n_in,
                              void* d_out, int out_size, void* d_ws, size_t ws_size,
                              hipStream_t stream) {
    const float* x    = (const float*)d_in[0];
    const float* w1   = (const float*)d_in[1];
    const float* s1   = (const float*)d_in[2];
    const float* t1   = (const float*)d_in[3];
    const float* w2   = (const float*)d_in[4];
    const float* s2   = (const float*)d_in[5];
    const float* t2   = (const float*)d_in[6];
    const float* w3   = (const float*)d_in[7];
    const float* s3   = (const float*)d_in[8];
    const float* t3   = (const float*)d_in[9];
    const float* fc1w = (const float*)d_in[10];
    const float* fc1b = (const float*)d_in[11];
    const float* fc2w = (const float*)d_in[12];
    const float* fc2b = (const float*)d_in[13];
    float* out = (float*)d_out;

    // Workspace layout (all fully overwritten every call):
    char* ws = (char*)d_ws;
    int*   idx  = (int*)ws;                                  // 655,360 B
    float* P    = (float*)(ws + (size_t)B_ * N_ * K_ * 4);   // 8 MB
    float* fc1T = P + (size_t)B_ * N_ * C3;                  // 131,072 B

    k_front<<<2576, 256, 0, stream>>>(x, w1, s1, t1, w2, s2, t2, w3, s3, t3,
                                      fc1w, idx, P, fc1T);
    k_gfc<<<B_ * 16, 256, 0, stream>>>(P, idx, fc1T, fc1b, fc2w, fc2b, out);
}

// Round 10
// 133.216 us; speedup vs baseline: 1.2219x; 1.0052x over previous
//
#include <hip/hip_runtime.h>
#include <hip/hip_bf16.h>

// Problem constants (B=32, N=256, K=20, channels 3->64->128->256, fc 256->128->40)
#define B_ 32
#define N_ 256
#define K_ 20
#define C1 64
#define C2 128
#define C3 256
#define F1 128
#define F2 40
#define NEG_INF (-3.402823466e38f)

// DPP controls
#define DPP_QUAD_XOR1 0xB1   // quad_perm [1,0,3,2]  (lane ^ 1)
#define DPP_QUAD_XOR2 0x4E   // quad_perm [2,3,0,1]  (lane ^ 2)
#define DPP_HALF_MIRR 0x141  // row_half_mirror      (lane ^ 7)
#define DPP_ROW_MIRR  0x140  // row_mirror           (lane ^ 15)
#define DPP_BCAST15   0x142  // lane 15 -> lanes 16-31, lane 47 -> 48-63
#define DPP_BCAST31   0x143  // lane 31 -> lanes 32-63

// Full-wave unsigned max, zero LDS ops: 4 row-local butterfly steps
// (masks {1,2,7,15} span the 4-bit row space) + 2 cumulative bcast steps.
// Result is complete in lane 63; bound_ctrl=true 0-fill is identity for
// unsigned max. Caller readlanes lane 63.
__device__ __forceinline__ unsigned wave_max_to_l63(unsigned v) {
    unsigned m;
    m = (unsigned)__builtin_amdgcn_update_dpp(0, (int)v, DPP_QUAD_XOR1, 0xF, 0xF, true);
    v = m > v ? m : v;
    m = (unsigned)__builtin_amdgcn_update_dpp(0, (int)v, DPP_QUAD_XOR2, 0xF, 0xF, true);
    v = m > v ? m : v;
    m = (unsigned)__builtin_amdgcn_update_dpp(0, (int)v, DPP_HALF_MIRR, 0xF, 0xF, true);
    v = m > v ? m : v;
    m = (unsigned)__builtin_amdgcn_update_dpp(0, (int)v, DPP_ROW_MIRR, 0xF, 0xF, true);
    v = m > v ? m : v;
    m = (unsigned)__builtin_amdgcn_update_dpp(0, (int)v, DPP_BCAST15, 0xF, 0xF, true);
    v = m > v ? m : v;
    m = (unsigned)__builtin_amdgcn_update_dpp(0, (int)v, DPP_BCAST31, 0xF, 0xF, true);
    v = m > v ? m : v;
    return v;
}

// ---------------------------------------------------------------------------
// NODE 1: three independent block families:
//   blocks [0,512):     per-point MLP, 16 pts/block. Thread = (oc-group,
//                       pt-quad) with the 4 pt-quad lanes ADJACENT -> weight
//                       addresses duplicate within a 4-lane group and merge in
//                       the coalescer (1x row coverage per block), while each
//                       activation ds_read_b128 feeds 4x FMAs.
//   blocks [512,2560):  per-point top-20, one wave per point, fully LDS-free:
//                       u32 monotone keys; DPP-only max reduce (readlane 63);
//                       exact lowest-index tie-break via ballot+ffs.
//                       Iteration 0 skipped: winner is provably self (v==0).
//   blocks [2560,2576): fc1 weight transpose fc1T[n][j] = fc1w[j][n].
// ---------------------------------------------------------------------------
__global__ __launch_bounds__(256) void k_front(const float* __restrict__ x,
    const float* __restrict__ w1, const float* __restrict__ s1, const float* __restrict__ b1,
    const float* __restrict__ w2, const float* __restrict__ s2, const float* __restrict__ b2,
    const float* __restrict__ w3, const float* __restrict__ s3, const float* __restrict__ b3,
    const float* __restrict__ fc1w,
    int* __restrict__ idx, float* __restrict__ P, float* __restrict__ fc1T) {

    __shared__ float smem[3136];        // mlp only: xs 64 | y1 1024 | y2 2048
    const int blk  = blockIdx.x;
    const int t    = threadIdx.x;
    const int lane = t & 63;
    const int wv   = t >> 6;

    if (blk < 512) {
        // ================== per-point MLP, 16 points/block ==================
        float* xs = smem;               // 48 used
        float* y1 = smem + 64;          // [c1][p] 64x16
        float* y2 = smem + 1088;        // [c2][p] 128x16
        const int pbase = blk * 16;
        const int og = t >> 2;          // oc-group 0..63 (4 adjacent lanes share)
        const int p0 = (t & 3) * 4;     // pt-quad

        if (t < 48) xs[t] = x[(size_t)pbase * 3 + t];
        __syncthreads();

        // ---- layer 1: 64 x 3; thread = (oc=lane, pt-quad=wv) ----
        {
            const int oc = lane;
            const float wa = w1[oc * 3 + 0], wb = w1[oc * 3 + 1], wc = w1[oc * 3 + 2];
            const float sc = s1[oc], sh = b1[oc];
            const int q0 = wv * 4;
            float4 v;
            #pragma unroll
            for (int p = 0; p < 4; ++p) {
                const int pp = q0 + p;
                float vv = wa * xs[pp * 3 + 0] + wb * xs[pp * 3 + 1] + wc * xs[pp * 3 + 2];
                (&v.x)[p] = fmaxf(vv * sc + sh, 0.0f);
            }
            *(float4*)&y1[oc * 16 + q0] = v;
        }
        __syncthreads();

        // ---- layer 2: 128oc x 64k; thread = (2-oc group og, pt-quad) ----
        {
            const int oc0 = og * 2;
            float acc[2][4] = {};
            for (int k = 0; k < C1; k += 4) {
                float4 a[4];
                #pragma unroll
                for (int kk = 0; kk < 4; ++kk)
                    a[kk] = *(const float4*)&y1[(k + kk) * 16 + p0];
                const float4 wA = *(const float4*)(w2 + (size_t)oc0 * C1 + k);       // 4-lane dup
                const float4 wB = *(const float4*)(w2 + (size_t)(oc0 + 1) * C1 + k); // merges
                #pragma unroll
                for (int kk = 0; kk < 4; ++kk) {
                    #pragma unroll
                    for (int p = 0; p < 4; ++p) {
                        acc[0][p] += (&wA.x)[kk] * (&a[kk].x)[p];
                        acc[1][p] += (&wB.x)[kk] * (&a[kk].x)[p];
                    }
                }
            }
            const float sc0 = s2[oc0], sh0 = b2[oc0];
            const float sc1 = s2[oc0 + 1], sh1 = b2[oc0 + 1];
            float4 v0, v1;
            #pragma unroll
            for (int p = 0; p < 4; ++p) {
                (&v0.x)[p] = fmaxf(acc[0][p] * sc0 + sh0, 0.0f);
                (&v1.x)[p] = fmaxf(acc[1][p] * sc1 + sh1, 0.0f);
            }
            *(float4*)&y2[oc0 * 16 + p0]       = v0;
            *(float4*)&y2[(oc0 + 1) * 16 + p0] = v1;
        }
        __syncthreads();

        // ---- layer 3: 256oc x 128k; thread = (4-oc group og, pt-quad) ----
        {
            const int oc0 = og * 4;
            float acc[4][4] = {};
            for (int k = 0; k < C2; k += 4) {
                float4 a[4];
                #pragma unroll
                for (int kk = 0; kk < 4; ++kk)
                    a[kk] = *(const float4*)&y2[(k + kk) * 16 + p0];
                float4 w[4];
                #pragma unroll
                for (int o = 0; o < 4; ++o)
                    w[o] = *(const float4*)(w3 + (size_t)(oc0 + o) * C2 + k);        // 4-lane dup
                #pragma unroll
                for (int o = 0; o < 4; ++o) {
                    #pragma unroll
                    for (int kk = 0; kk < 4; ++kk) {
                        const float wvv = (&w[o].x)[kk];
                        #pragma unroll
                        for (int p = 0; p < 4; ++p)
                            acc[o][p] += wvv * (&a[kk].x)[p];
                    }
                }
            }
            const float4 sc = *(const float4*)&s3[oc0];
            const float4 sh = *(const float4*)&b3[oc0];
            #pragma unroll
            for (int p = 0; p < 4; ++p) {
                float4 v;
                #pragma unroll
                for (int o = 0; o < 4; ++o)
                    (&v.x)[o] = fmaxf(acc[o][p] * (&sc.x)[o] + (&sh.x)[o], 0.0f);
                *(float4*)&P[(size_t)(pbase + p0 + p) * C3 + oc0] = v;
            }
        }

    } else if (blk < 2560) {
        // ================== top-20, one wave per point, LDS-free ==================
        const int tb = blk - 512;
        const int b  = tb >> 6;
        const int n  = ((tb & 63) << 2) | wv;
        const int bn = (b << 8) | n;
        const float* xb = x + (size_t)b * N_ * 3;

        const float nx = xb[n * 3 + 0], ny = xb[n * 3 + 1], nz = xb[n * 3 + 2];
        const float xxn = nx * nx + ny * ny + nz * nz;

        unsigned k0, k1, k2, k3;
        {
            unsigned kk[4];
            #pragma unroll
            for (int i = 0; i < 4; ++i) {
                const int m = lane + (i << 6);
                const float cx = xb[m * 3 + 0], cy = xb[m * 3 + 1], cz = xb[m * 3 + 2];
                const float xxm = cx * cx + cy * cy + cz * cz;
                const float v = 2.0f * (nx * cx + ny * cy + nz * cz) - xxn - xxm;
                const unsigned u = __float_as_uint(v);
                kk[i] = (u & 0x80000000u) ? ~u : (u | 0x80000000u);   // monotone
            }
            k0 = kk[0]; k1 = kk[1]; k2 = kk[2]; k3 = kk[3];
        }

        // Iteration 0: winner is provably the self-point (pairwise value is
        // exactly 0.0f for m==n, strictly negative otherwise).
        int mine = (lane == 0) ? n : 0;
        if (lane == (n & 63)) {
            const int slot = n >> 6;
            if      (slot == 0) k0 = 0u;
            else if (slot == 1) k1 = 0u;
            else if (slot == 2) k2 = 0u;
            else                k3 = 0u;
        }

        #pragma unroll 1
        for (int it = 1; it < K_; ++it) {
            unsigned ra = k0 > k1 ? k0 : k1;
            unsigned rb = k2 > k3 ? k2 : k3;
            const unsigned full = wave_max_to_l63(ra > rb ? ra : rb);
            const unsigned M = (unsigned)__builtin_amdgcn_readlane((int)full, 63);
            const unsigned long long b0 = __ballot(k0 == M);
            const unsigned long long b1 = __ballot(k1 == M);
            const unsigned long long b2m = __ballot(k2 == M);
            const unsigned long long b3m = __ballot(k3 == M);
            int ri;
            if      (b0)  ri = __ffsll((long long)b0) - 1;
            else if (b1)  ri = 64  + __ffsll((long long)b1) - 1;
            else if (b2m) ri = 128 + __ffsll((long long)b2m) - 1;
            else          ri = 192 + __ffsll((long long)b3m) - 1;
            if (lane == it) mine = ri;
            if (lane == (ri & 63)) {
                const int slot = ri >> 6;
                if      (slot == 0) k0 = 0u;
                else if (slot == 1) k1 = 0u;
                else if (slot == 2) k2 = 0u;
                else                k3 = 0u;
            }
        }
        if (lane < K_) idx[(size_t)bn * K_ + lane] = mine;

    } else {
        // ================== fc1 weight transpose ==================
        const int g = (blk - 2560) * 256 + t;   // 0..4095
        #pragma unroll
        for (int i = 0; i < 8; ++i) {           // 32768 elems
            const int e = g + i * 4096;
            const int j = e >> 8, n = e & 255;
            fc1T[n * F1 + j] = fc1w[e];
        }
    }
}

// ---------------------------------------------------------------------------
// NODE 2: FUSED gather-max + fc1(relu) + fc2 (unchanged since R5).
// 512 blocks = (b, 16-ch tile) x 256 threads.
// ---------------------------------------------------------------------------
__global__ __launch_bounds__(256) void k_gfc(const float* __restrict__ P,
                                             const int* __restrict__ idx,
                                             const float* __restrict__ fc1T,
                                             const float* __restrict__ fc1b,
                                             const float* __restrict__ fc2w,
                                             const float* __restrict__ fc2b,
                                             float* __restrict__ out) {
    const int b    = blockIdx.x >> 4;
    const int ch0  = (blockIdx.x & 15) * 16;
    const int t    = threadIdx.x;
    const int lane = t & 63;

    __shared__ float Ht[N_ * 16];       // [n][ci], 16 KB
    __shared__ float gl[16 * 132];      // [ci][j], padded stride 132
    __shared__ float w2l[F2 * 129];     // [m][j], padded (129 = 1 mod 32)

    for (int e = t; e < F2 * F1; e += 256)
        w2l[(e >> 7) * 129 + (e & 127)] = fc2w[e];

    // ---- stage A: gather-max into Ht ----
    {
        const int q  = t & 3;           // ch-quad
        const int nl = t >> 2;          // n within quarter-pass
        const float* Pq = P + (size_t)b * N_ * C3 + ch0 + q * 4;
        #pragma unroll
        for (int r = 0; r < 4; ++r) {
            const int n = r * 64 + nl;
            const int* ib = idx + ((size_t)((b << 8) | n)) * K_;
            float4 m = make_float4(NEG_INF, NEG_INF, NEG_INF, NEG_INF);
            #pragma unroll
            for (int j = 0; j < K_; ++j) {
                const int id = ib[j];
                const float4 p = *(const float4*)(Pq + (size_t)id * C3);
                m.x = fmaxf(m.x, p.x);
                m.y = fmaxf(m.y, p.y);
                m.z = fmaxf(m.z, p.z);
                m.w = fmaxf(m.w, p.w);
            }
            *(float4*)&Ht[n * 16 + q * 4] = m;
        }
    }
    __syncthreads();

    // ---- stage B: fc1 + relu -> gl[ci][j] ----
    {
        const int c0 = (t >> 6) * 4;    // wave's ch-quad
        float acc[2][4] = {};
        #pragma unroll 4
        for (int n = 0; n < N_; ++n) {
            const float2 w = *(const float2*)&fc1T[n * F1 + lane * 2];  // coalesced
            const float4 a = *(const float4*)&Ht[n * 16 + c0];          // broadcast
            #pragma unroll
            for (int c = 0; c < 4; ++c) {
                acc[0][c] += w.x * (&a.x)[c];
                acc[1][c] += w.y * (&a.x)[c];
            }
        }
        const float bb0 = fc1b[lane * 2], bb1 = fc1b[lane * 2 + 1];
        #pragma unroll
        for (int c = 0; c < 4; ++c) {
            float2 v;
            v.x = fmaxf(acc[0][c] + bb0, 0.0f);
            v.y = fmaxf(acc[1][c] + bb1, 0.0f);
            *(float2*)&gl[(c0 + c) * 132 + lane * 2] = v;
        }
    }
    __syncthreads();

    // ---- stage C: fc2 -> out ----
    for (int o = t; o < 16 * F2; o += 256) {
        const int ci = o / F2;
        const int m  = o % F2;
        float acc = fc2b[m];
        const float* wr = w2l + m * 129;
        const float* gr = gl + ci * 132;
        #pragma unroll 4
        for (int j = 0; j < F1; ++j)
            acc += wr[j] * gr[j];
        out[((size_t)(b * C3 + ch0 + ci)) * F2 + m] = acc;
    }
}

// ---------------------------------------------------------------------------
extern "C" void kernel_launch(void* const* d_in, const int* in_sizes, int n_in,
                              void* d_out, int out_size, void* d_ws, size_t ws_size,
                              hipStream_t stream) {
    const float* x    = (const float*)d_in[0];
    const float* w1   = (const float*)d_in[1];
    const float* s1   = (const float*)d_in[2];
    const float* t1   = (const float*)d_in[3];
    const float* w2   = (const float*)d_in[4];
    const float* s2   = (const float*)d_in[5];
    const float* t2   = (const float*)d_in[6];
    const float* w3   = (const float*)d_in[7];
    const float* s3   = (const float*)d_in[8];
    const float* t3   = (const float*)d_in[9];
    const float* fc1w = (const float*)d_in[10];
    const float* fc1b = (const float*)d_in[11];
    const float* fc2w = (const float*)d_in[12];
    const float* fc2b = (const float*)d_in[13];
    float* out = (float*)d_out;

    // Workspace layout (all fully overwritten every call):
    char* ws = (char*)d_ws;
    int*   idx  = (int*)ws;                                  // 655,360 B
    float* P    = (float*)(ws + (size_t)B_ * N_ * K_ * 4);   // 8 MB
    float* fc1T = P + (size_t)B_ * N_ * C3;                  // 131,072 B

    k_front<<<2576, 256, 0, stream>>>(x, w1, s1, t1, w2, s2, t2, w3, s3, t3,
                                      fc1w, idx, P, fc1T);
    k_gfc<<<B_ * 16, 256, 0, stream>>>(P, idx, fc1T, fc1b, fc2w, fc2b, out);
}